// Round 1
// baseline (591.146 us; speedup 1.0000x reference)
//
#include <hip/hip_runtime.h>

#define BB 128
#define SS 512
#define NPOS (BB*SS)          // 65536
#define DD 256
#define KIND_D 8
#define EXPR_D 512
#define KOS_VOCAB 256
#define NUM_IDS 8192
#define IDENTIFIER_KIND 3
#define TR 32                 // rows per block tile

// ---------------- Kernel 1: masked_scatter rank scan -> sel[] ----------------
// sel[i] = identifier_indices[rank_id[i]]            if kind==3
//        = NUM_IDS + kos_token_index[rank_kos[i]]    if kind in {4,5,6}
//        = -1                                        otherwise
__global__ __launch_bounds__(1024) void scan_kernel(const int* __restrict__ token_type,
                                                    const int* __restrict__ kos_idx,
                                                    const int* __restrict__ id_idx,
                                                    int* __restrict__ sel) {
    __shared__ int s_id[1024];
    __shared__ int s_kos[1024];
    const int t = threadIdx.x;
    const int base = t * 64;
    int cid = 0, ckos = 0;
    for (int i = 0; i < 64; ++i) {
        int k = token_type[base + i];
        cid  += (k == IDENTIFIER_KIND);
        ckos += (k >= 4 && k <= 6);
    }
    s_id[t] = cid; s_kos[t] = ckos;
    __syncthreads();
    // Hillis-Steele inclusive scan over 1024 per-thread counts
    for (int off = 1; off < 1024; off <<= 1) {
        int vi = (t >= off) ? s_id[t - off]  : 0;
        int vk = (t >= off) ? s_kos[t - off] : 0;
        __syncthreads();
        s_id[t] += vi; s_kos[t] += vk;
        __syncthreads();
    }
    int rid  = (t > 0) ? s_id[t - 1]  : 0;   // exclusive prefix for this chunk
    int rkos = (t > 0) ? s_kos[t - 1] : 0;
    for (int i = 0; i < 64; ++i) {
        int k = token_type[base + i];
        int s = -1;
        if (k == IDENTIFIER_KIND)      { s = id_idx[rid]; ++rid; }
        else if (k >= 4 && k <= 6)     { s = NUM_IDS + kos_idx[rkos]; ++rkos; }
        sel[base + i] = s;
    }
}

// ---------------- Kernel 2: kind contribution rows (8 x 512) ----------------
// kindc[kind][j] = sum_d kind_emb[kind][d] * W_proj[d][j] + b_proj[j]
__global__ __launch_bounds__(512) void kindc_kernel(const float* __restrict__ kind_emb,
                                                    const float* __restrict__ Wp,
                                                    const float* __restrict__ bp,
                                                    float* __restrict__ kindc) {
    int j = threadIdx.x;
    float bias = bp[j];
    for (int kind = 0; kind < 8; ++kind) {
        float a = bias;
        #pragma unroll
        for (int d = 0; d < KIND_D; ++d)
            a = fmaf(kind_emb[kind * KIND_D + d], Wp[d * EXPR_D + j], a);
        kindc[kind * EXPR_D + j] = a;
    }
}

// ---------------- Kernel 3: projected source table P = [enc_ids; kos_emb] @ W_proj[8:,:] ----
// P is [NUM_IDS + KOS_VOCAB][EXPR_D]
__global__ __launch_bounds__(256) void proj_kernel(const float* __restrict__ enc_ids,
                                                   const float* __restrict__ kos_emb,
                                                   const float* __restrict__ Wp,
                                                   float* __restrict__ P) {
    __shared__ float xs[TR][DD];   // 32 KiB
    const int row0 = blockIdx.x * TR;
    const int t = threadIdx.x;
    for (int r = 0; r < TR; ++r) {
        int row = row0 + r;
        const float* src = (row < NUM_IDS) ? &enc_ids[(size_t)row * DD]
                                           : &kos_emb[(size_t)(row - NUM_IDS) * DD];
        xs[r][t] = src[t];
    }
    __syncthreads();
    const int tcol = t & 63, trow = t >> 6;
    const int c0 = tcol * 8, r0 = trow * 8;
    const float* W1p = Wp + (size_t)KIND_D * EXPR_D;   // rows 8..263
    float acc[8][8] = {};
    for (int k = 0; k < DD; k += 4) {
        float4 hv[8];
        #pragma unroll
        for (int r = 0; r < 8; ++r) hv[r] = *(const float4*)&xs[r0 + r][k];
        #pragma unroll
        for (int kk = 0; kk < 4; ++kk) {
            float4 w0 = *(const float4*)&W1p[(size_t)(k + kk) * EXPR_D + c0];
            float4 w1 = *(const float4*)&W1p[(size_t)(k + kk) * EXPR_D + c0 + 4];
            float wc[8] = {w0.x, w0.y, w0.z, w0.w, w1.x, w1.y, w1.z, w1.w};
            #pragma unroll
            for (int r = 0; r < 8; ++r) {
                float hr = (kk == 0) ? hv[r].x : (kk == 1) ? hv[r].y : (kk == 2) ? hv[r].z : hv[r].w;
                #pragma unroll
                for (int c = 0; c < 8; ++c) acc[r][c] = fmaf(hr, wc[c], acc[r][c]);
            }
        }
    }
    #pragma unroll
    for (int r = 0; r < 8; ++r) {
        float* dst = &P[(size_t)(row0 + r0 + r) * EXPR_D + c0];
        *(float4*)&dst[0] = make_float4(acc[r][0], acc[r][1], acc[r][2], acc[r][3]);
        *(float4*)&dst[4] = make_float4(acc[r][4], acc[r][5], acc[r][6], acc[r][7]);
    }
}

// ---------------- Kernel 4: fused gather + layer1-assemble + layer2 GEMM ----------------
__global__ __launch_bounds__(256) void mlp2_kernel(const int* __restrict__ token_type,
                                                   const int* __restrict__ sel,
                                                   const float* __restrict__ P,
                                                   const float* __restrict__ kindc,
                                                   const float* __restrict__ W2,
                                                   const float* __restrict__ b2,
                                                   float* __restrict__ out) {
    __shared__ float h[TR][EXPR_D];   // 64 KiB
    const int row0 = blockIdx.x * TR;
    const int t = threadIdx.x;

    // Phase A: h[r][:] = relu(P[sel] (or 0) + kindc[kind])
    for (int r = 0; r < TR; ++r) {
        int row = row0 + r;
        int g = sel[row];
        int kind = token_type[row];
        float2 kc = *(const float2*)&kindc[kind * EXPR_D + t * 2];
        float2 v = kc;
        if (g >= 0) {
            float2 p = *(const float2*)&P[(size_t)g * EXPR_D + t * 2];
            v.x += p.x; v.y += p.y;
        }
        h[r][t * 2]     = fmaxf(v.x, 0.f);
        h[r][t * 2 + 1] = fmaxf(v.y, 0.f);
    }
    __syncthreads();

    // Phase B: out_tile = relu(h @ W2 + b2)
    const int tcol = t & 63, trow = t >> 6;
    const int c0 = tcol * 8, r0 = trow * 8;
    float acc[8][8] = {};
    for (int k = 0; k < EXPR_D; k += 4) {
        float4 hv[8];
        #pragma unroll
        for (int r = 0; r < 8; ++r) hv[r] = *(const float4*)&h[r0 + r][k];
        #pragma unroll
        for (int kk = 0; kk < 4; ++kk) {
            float4 w0 = *(const float4*)&W2[(size_t)(k + kk) * EXPR_D + c0];
            float4 w1 = *(const float4*)&W2[(size_t)(k + kk) * EXPR_D + c0 + 4];
            float wc[8] = {w0.x, w0.y, w0.z, w0.w, w1.x, w1.y, w1.z, w1.w};
            #pragma unroll
            for (int r = 0; r < 8; ++r) {
                float hr = (kk == 0) ? hv[r].x : (kk == 1) ? hv[r].y : (kk == 2) ? hv[r].z : hv[r].w;
                #pragma unroll
                for (int c = 0; c < 8; ++c) acc[r][c] = fmaf(hr, wc[c], acc[r][c]);
            }
        }
    }
    float4 bv0 = *(const float4*)&b2[c0];
    float4 bv1 = *(const float4*)&b2[c0 + 4];
    float bb[8] = {bv0.x, bv0.y, bv0.z, bv0.w, bv1.x, bv1.y, bv1.z, bv1.w};
    #pragma unroll
    for (int r = 0; r < 8; ++r) {
        float* dst = &out[(size_t)(row0 + r0 + r) * EXPR_D + c0];
        float4 o0, o1;
        o0.x = fmaxf(acc[r][0] + bb[0], 0.f); o0.y = fmaxf(acc[r][1] + bb[1], 0.f);
        o0.z = fmaxf(acc[r][2] + bb[2], 0.f); o0.w = fmaxf(acc[r][3] + bb[3], 0.f);
        o1.x = fmaxf(acc[r][4] + bb[4], 0.f); o1.y = fmaxf(acc[r][5] + bb[5], 0.f);
        o1.z = fmaxf(acc[r][6] + bb[6], 0.f); o1.w = fmaxf(acc[r][7] + bb[7], 0.f);
        *(float4*)&dst[0] = o0;
        *(float4*)&dst[4] = o1;
    }
}

extern "C" void kernel_launch(void* const* d_in, const int* in_sizes, int n_in,
                              void* d_out, int out_size, void* d_ws, size_t ws_size,
                              hipStream_t stream) {
    const int*   token_type = (const int*)d_in[0];
    const int*   kos_idx    = (const int*)d_in[1];
    const int*   id_idx     = (const int*)d_in[2];
    const float* enc_ids    = (const float*)d_in[3];
    const float* kind_emb   = (const float*)d_in[4];
    const float* kos_emb    = (const float*)d_in[5];
    const float* Wp         = (const float*)d_in[6];
    const float* bp         = (const float*)d_in[7];
    const float* W2         = (const float*)d_in[8];
    const float* b2         = (const float*)d_in[9];
    float* out = (float*)d_out;

    char* ws = (char*)d_ws;
    int*   sel   = (int*)ws;                                       // 256 KiB
    float* kindc = (float*)(ws + (size_t)NPOS * 4);                // 16 KiB
    float* P     = (float*)(ws + (size_t)NPOS * 4 + 8 * EXPR_D * 4); // ~17.3 MiB

    hipLaunchKernelGGL(scan_kernel, dim3(1), dim3(1024), 0, stream,
                       token_type, kos_idx, id_idx, sel);
    hipLaunchKernelGGL(kindc_kernel, dim3(1), dim3(512), 0, stream,
                       kind_emb, Wp, bp, kindc);
    hipLaunchKernelGGL(proj_kernel, dim3((NUM_IDS + KOS_VOCAB) / TR), dim3(256), 0, stream,
                       enc_ids, kos_emb, Wp, P);
    hipLaunchKernelGGL(mlp2_kernel, dim3(NPOS / TR), dim3(256), 0, stream,
                       token_type, sel, P, kindc, W2, b2, out);
}

// Round 2
// 351.149 us; speedup vs baseline: 1.6835x; 1.6835x over previous
//
#include <hip/hip_runtime.h>
#include <hip/hip_bf16.h>

#define BB 128
#define SS 512
#define NPOS (BB*SS)          // 65536
#define DD 256
#define KIND_D 8
#define EXPR_D 512
#define KOS_VOCAB 256
#define NUM_IDS 8192
#define IDENTIFIER_KIND 3
#define TR 32                 // rows per block tile (proj kernel)

typedef unsigned short u16;
typedef __attribute__((ext_vector_type(8))) short s16x8;   // 8 bf16 (4 VGPRs)
typedef __attribute__((ext_vector_type(4))) float f32x4;

__device__ __forceinline__ u16 bf16bits(float v) {
    __hip_bfloat16 h = __float2bfloat16(v);
    return *(u16*)&h;
}
__device__ __forceinline__ float bf16tof(u16 b) {
    __hip_bfloat16 h = *(__hip_bfloat16*)&b;
    return __bfloat162float(h);
}

// ---------------- Kernel 1: masked_scatter rank scan -> sel[] ----------------
__global__ __launch_bounds__(1024) void scan_kernel(const int* __restrict__ token_type,
                                                    const int* __restrict__ kos_idx,
                                                    const int* __restrict__ id_idx,
                                                    int* __restrict__ sel) {
    __shared__ int s_id[1024];
    __shared__ int s_kos[1024];
    const int t = threadIdx.x;
    const int base = t * 64;
    int cid = 0, ckos = 0;
    for (int i = 0; i < 64; ++i) {
        int k = token_type[base + i];
        cid  += (k == IDENTIFIER_KIND);
        ckos += (k >= 4 && k <= 6);
    }
    s_id[t] = cid; s_kos[t] = ckos;
    __syncthreads();
    for (int off = 1; off < 1024; off <<= 1) {
        int vi = (t >= off) ? s_id[t - off]  : 0;
        int vk = (t >= off) ? s_kos[t - off] : 0;
        __syncthreads();
        s_id[t] += vi; s_kos[t] += vk;
        __syncthreads();
    }
    int rid  = (t > 0) ? s_id[t - 1]  : 0;
    int rkos = (t > 0) ? s_kos[t - 1] : 0;
    for (int i = 0; i < 64; ++i) {
        int k = token_type[base + i];
        int s = -1;
        if (k == IDENTIFIER_KIND)      { s = id_idx[rid]; ++rid; }
        else if (k >= 4 && k <= 6)     { s = NUM_IDS + kos_idx[rkos]; ++rkos; }
        sel[base + i] = s;
    }
}

// ---------------- Kernel 2: kind contribution rows (8 x 512) ----------------
__global__ __launch_bounds__(512) void kindc_kernel(const float* __restrict__ kind_emb,
                                                    const float* __restrict__ Wp,
                                                    const float* __restrict__ bp,
                                                    float* __restrict__ kindc) {
    int j = threadIdx.x;
    float bias = bp[j];
    for (int kind = 0; kind < 8; ++kind) {
        float a = bias;
        #pragma unroll
        for (int d = 0; d < KIND_D; ++d)
            a = fmaf(kind_emb[kind * KIND_D + d], Wp[d * EXPR_D + j], a);
        kindc[kind * EXPR_D + j] = a;
    }
}

// ---------------- Kernel 3: P = [enc_ids; kos_emb] @ W_proj[8:,:] (fp32) ----
__global__ __launch_bounds__(256) void proj_kernel(const float* __restrict__ enc_ids,
                                                   const float* __restrict__ kos_emb,
                                                   const float* __restrict__ Wp,
                                                   float* __restrict__ P) {
    __shared__ float xs[TR][DD];   // 32 KiB
    const int row0 = blockIdx.x * TR;
    const int t = threadIdx.x;
    for (int r = 0; r < TR; ++r) {
        int row = row0 + r;
        const float* src = (row < NUM_IDS) ? &enc_ids[(size_t)row * DD]
                                           : &kos_emb[(size_t)(row - NUM_IDS) * DD];
        xs[r][t] = src[t];
    }
    __syncthreads();
    const int tcol = t & 63, trow = t >> 6;
    const int c0 = tcol * 8, r0 = trow * 8;
    const float* W1p = Wp + (size_t)KIND_D * EXPR_D;
    float acc[8][8] = {};
    for (int k = 0; k < DD; k += 4) {
        float4 hv[8];
        #pragma unroll
        for (int r = 0; r < 8; ++r) hv[r] = *(const float4*)&xs[r0 + r][k];
        #pragma unroll
        for (int kk = 0; kk < 4; ++kk) {
            float4 w0 = *(const float4*)&W1p[(size_t)(k + kk) * EXPR_D + c0];
            float4 w1 = *(const float4*)&W1p[(size_t)(k + kk) * EXPR_D + c0 + 4];
            float wc[8] = {w0.x, w0.y, w0.z, w0.w, w1.x, w1.y, w1.z, w1.w};
            #pragma unroll
            for (int r = 0; r < 8; ++r) {
                float hr = (kk == 0) ? hv[r].x : (kk == 1) ? hv[r].y : (kk == 2) ? hv[r].z : hv[r].w;
                #pragma unroll
                for (int c = 0; c < 8; ++c) acc[r][c] = fmaf(hr, wc[c], acc[r][c]);
            }
        }
    }
    #pragma unroll
    for (int r = 0; r < 8; ++r) {
        float* dst = &P[(size_t)(row0 + r0 + r) * EXPR_D + c0];
        *(float4*)&dst[0] = make_float4(acc[r][0], acc[r][1], acc[r][2], acc[r][3]);
        *(float4*)&dst[4] = make_float4(acc[r][4], acc[r][5], acc[r][6], acc[r][7]);
    }
}

// ---------------- Kernel 4: transpose + bf16 hi/lo split of W2 ----------------
// W2[k][n] (512x512 f32) -> Whi/Wlo[n][k] (512x512 bf16)
__global__ __launch_bounds__(256) void splitw_kernel(const float* __restrict__ W2,
                                                     u16* __restrict__ Whi,
                                                     u16* __restrict__ Wlo) {
    __shared__ float tile[32][33];
    const int n0 = blockIdx.x * 32;
    const int k0 = blockIdx.y * 32;
    const int t = threadIdx.x;
    const int lj = t & 31, li = t >> 5;   // li 0..7
    #pragma unroll
    for (int p = 0; p < 4; ++p) {
        int i = li + p * 8;
        tile[i][lj] = W2[(size_t)(k0 + i) * EXPR_D + n0 + lj];
    }
    __syncthreads();
    #pragma unroll
    for (int p = 0; p < 4; ++p) {
        int j = li + p * 8;
        float v = tile[lj][j];
        u16 hb = bf16bits(v);
        float r = v - bf16tof(hb);
        u16 lb = bf16bits(r);
        size_t o = (size_t)(n0 + j) * EXPR_D + k0 + lj;
        Whi[o] = hb;
        Wlo[o] = lb;
    }
}

// ---------------- Kernel 5: fused gather + layer1 + split-bf16 MFMA layer2 ----
// 128x128 tile, BK=64, 4 waves (2x2), 16x16x32 bf16 MFMA, XOR-swizzled LDS.
__global__ __launch_bounds__(256) void mlp2_kernel(const int* __restrict__ token_type,
                                                   const int* __restrict__ sel,
                                                   const float* __restrict__ P,
                                                   const float* __restrict__ kindc,
                                                   const u16* __restrict__ Whi,
                                                   const u16* __restrict__ Wlo,
                                                   const float* __restrict__ b2,
                                                   float* __restrict__ out) {
    __shared__ u16 sAhi[128 * 64];   // 16 KiB each; 64 KiB total
    __shared__ u16 sAlo[128 * 64];
    __shared__ u16 sBhi[128 * 64];
    __shared__ u16 sBlo[128 * 64];

    const int t = threadIdx.x;
    const int row0 = blockIdx.x * 128;
    const int col0 = blockIdx.y * 128;

    // staging decomposition: thread covers rows p*16 + ar, k-cols [ac, ac+4)
    const int ar = t >> 4;            // 0..15
    const int ac = (t & 15) * 4;      // 0..60

    int gsel[8], gkind[8];
    #pragma unroll
    for (int p = 0; p < 8; ++p) {
        int row = row0 + p * 16 + ar;
        gsel[p]  = sel[row];
        gkind[p] = token_type[row];
    }

    const int lane = t & 63;
    const int wid  = t >> 6;
    const int wr = wid >> 1, wc = wid & 1;     // wave -> 64x64 quadrant
    const int lrow = lane & 15, lkg = lane >> 4;

    f32x4 acc[4][4];
    #pragma unroll
    for (int mi = 0; mi < 4; ++mi)
        #pragma unroll
        for (int ni = 0; ni < 4; ++ni)
            acc[mi][ni] = (f32x4){0.f, 0.f, 0.f, 0.f};

    for (int kc = 0; kc < 8; ++kc) {
        const int kbase = kc * 64;
        __syncthreads();   // previous MFMA phase finished reading LDS

        // ---- build A tile: h = relu(kindc[kind] + P[g]) split to bf16 hi/lo
        #pragma unroll
        for (int p = 0; p < 8; ++p) {
            int row = p * 16 + ar;
            int g = gsel[p], kind = gkind[p];
            f32x4 v = *(const f32x4*)&kindc[kind * EXPR_D + kbase + ac];
            if (g >= 0) {
                f32x4 pv = *(const f32x4*)&P[(size_t)g * EXPR_D + kbase + ac];
                v += pv;
            }
            float c0v = fmaxf(v.x, 0.f), c1v = fmaxf(v.y, 0.f);
            float c2v = fmaxf(v.z, 0.f), c3v = fmaxf(v.w, 0.f);
            u16 h0 = bf16bits(c0v), h1 = bf16bits(c1v), h2 = bf16bits(c2v), h3 = bf16bits(c3v);
            u16 l0 = bf16bits(c0v - bf16tof(h0));
            u16 l1 = bf16bits(c1v - bf16tof(h1));
            u16 l2 = bf16bits(c2v - bf16tof(h2));
            u16 l3 = bf16bits(c3v - bf16tof(h3));
            int off = row * 128 + ((ac * 2) ^ ((row & 7) << 4));
            *(ushort4*)((char*)sAhi + off) = make_ushort4(h0, h1, h2, h3);
            *(ushort4*)((char*)sAlo + off) = make_ushort4(l0, l1, l2, l3);
        }
        // ---- load B tile: Whi/Wlo[n][k] row-major, same swizzle
        #pragma unroll
        for (int p = 0; p < 8; ++p) {
            int n = p * 16 + ar;
            size_t src = (size_t)(col0 + n) * EXPR_D + kbase + ac;
            ushort4 hv = *(const ushort4*)&Whi[src];
            ushort4 lv = *(const ushort4*)&Wlo[src];
            int off = n * 128 + ((ac * 2) ^ ((n & 7) << 4));
            *(ushort4*)((char*)sBhi + off) = hv;
            *(ushort4*)((char*)sBlo + off) = lv;
        }
        __syncthreads();

        // ---- MFMA: acc += Ahi*Bhi + Ahi*Blo + Alo*Bhi
        #pragma unroll
        for (int ks = 0; ks < 2; ++ks) {
            s16x8 ah[4], al[4], bh[4], bl[4];
            #pragma unroll
            for (int mi = 0; mi < 4; ++mi) {
                int row = wr * 64 + mi * 16 + lrow;
                int off = row * 128 + ((ks * 64 + lkg * 16) ^ ((row & 7) << 4));
                ah[mi] = *(const s16x8*)((const char*)sAhi + off);
                al[mi] = *(const s16x8*)((const char*)sAlo + off);
            }
            #pragma unroll
            for (int ni = 0; ni < 4; ++ni) {
                int row = wc * 64 + ni * 16 + lrow;
                int off = row * 128 + ((ks * 64 + lkg * 16) ^ ((row & 7) << 4));
                bh[ni] = *(const s16x8*)((const char*)sBhi + off);
                bl[ni] = *(const s16x8*)((const char*)sBlo + off);
            }
            #pragma unroll
            for (int mi = 0; mi < 4; ++mi)
                #pragma unroll
                for (int ni = 0; ni < 4; ++ni) {
                    acc[mi][ni] = __builtin_amdgcn_mfma_f32_16x16x32_bf16(ah[mi], bh[ni], acc[mi][ni], 0, 0, 0);
                    acc[mi][ni] = __builtin_amdgcn_mfma_f32_16x16x32_bf16(ah[mi], bl[ni], acc[mi][ni], 0, 0, 0);
                    acc[mi][ni] = __builtin_amdgcn_mfma_f32_16x16x32_bf16(al[mi], bh[ni], acc[mi][ni], 0, 0, 0);
                }
        }
    }

    // ---- epilogue: bias + relu, C/D map col=lane&15, row=(lane>>4)*4+reg
    #pragma unroll
    for (int ni = 0; ni < 4; ++ni) {
        int col = col0 + wc * 64 + ni * 16 + lrow;
        float bias = b2[col];
        #pragma unroll
        for (int mi = 0; mi < 4; ++mi) {
            int rbase = row0 + wr * 64 + mi * 16 + lkg * 4;
            #pragma unroll
            for (int j = 0; j < 4; ++j)
                out[(size_t)(rbase + j) * EXPR_D + col] = fmaxf(acc[mi][ni][j] + bias, 0.f);
        }
    }
}

extern "C" void kernel_launch(void* const* d_in, const int* in_sizes, int n_in,
                              void* d_out, int out_size, void* d_ws, size_t ws_size,
                              hipStream_t stream) {
    const int*   token_type = (const int*)d_in[0];
    const int*   kos_idx    = (const int*)d_in[1];
    const int*   id_idx     = (const int*)d_in[2];
    const float* enc_ids    = (const float*)d_in[3];
    const float* kind_emb   = (const float*)d_in[4];
    const float* kos_emb    = (const float*)d_in[5];
    const float* Wp         = (const float*)d_in[6];
    const float* bp         = (const float*)d_in[7];
    const float* W2         = (const float*)d_in[8];
    const float* b2         = (const float*)d_in[9];
    float* out = (float*)d_out;

    char* ws = (char*)d_ws;
    int*   sel   = (int*)ws;                                   // 256 KiB
    float* kindc = (float*)(ws + 262144);                      // 16 KiB
    float* P     = (float*)(ws + 262144 + 16384);              // 17.3 MiB
    u16*   Whi   = (u16*)(ws + 262144 + 16384 + (size_t)(NUM_IDS + KOS_VOCAB) * EXPR_D * 4);
    u16*   Wlo   = Whi + (size_t)EXPR_D * EXPR_D;

    hipLaunchKernelGGL(scan_kernel, dim3(1), dim3(1024), 0, stream,
                       token_type, kos_idx, id_idx, sel);
    hipLaunchKernelGGL(kindc_kernel, dim3(1), dim3(512), 0, stream,
                       kind_emb, Wp, bp, kindc);
    hipLaunchKernelGGL(splitw_kernel, dim3(16, 16), dim3(256), 0, stream,
                       W2, Whi, Wlo);
    hipLaunchKernelGGL(proj_kernel, dim3((NUM_IDS + KOS_VOCAB) / TR), dim3(256), 0, stream,
                       enc_ids, kos_emb, Wp, P);
    hipLaunchKernelGGL(mlp2_kernel, dim3(NPOS / 128, EXPR_D / 128), dim3(256), 0, stream,
                       token_type, sel, P, kindc, Whi, Wlo, b2, out);
}

// Round 3
// 234.948 us; speedup vs baseline: 2.5161x; 1.4946x over previous
//
#include <hip/hip_runtime.h>
#include <hip/hip_bf16.h>

#define BB 128
#define SS 512
#define NPOS (BB*SS)          // 65536
#define DD 256
#define KIND_D 8
#define EXPR_D 512
#define KOS_VOCAB 256
#define NUM_IDS 8192
#define IDENTIFIER_KIND 3
#define TR 32                 // rows per block tile (proj kernel)

typedef unsigned short u16;
typedef __attribute__((ext_vector_type(8))) short s16x8;           // 8 bf16 (4 VGPRs)
typedef __attribute__((ext_vector_type(8))) unsigned short u16x8;  // 16B store unit
typedef __attribute__((ext_vector_type(4))) float f32x4;

__device__ __forceinline__ u16 bf16bits(float v) {
    __hip_bfloat16 h = __float2bfloat16(v);
    return *(u16*)&h;
}
__device__ __forceinline__ float bf16tof(u16 b) {
    __hip_bfloat16 h = *(__hip_bfloat16*)&b;
    return __bfloat162float(h);
}

// ---------------- Kernel 1: masked_scatter rank scan -> sel[] ----------------
// Coalesced ballot-based scan: 1 block, 64 chunks of 1024 contiguous elements.
__global__ __launch_bounds__(1024) void scan_kernel(const int* __restrict__ token_type,
                                                    const int* __restrict__ kos_idx,
                                                    const int* __restrict__ id_idx,
                                                    int* __restrict__ sel) {
    __shared__ int swid[16], swkos[16];
    const int t = threadIdx.x, lane = t & 63, wave = t >> 6;
    int run_id = 0, run_kos = 0;
    for (int c = 0; c < 64; ++c) {
        int idx = c * 1024 + t;
        int k = token_type[idx];
        bool fid  = (k == IDENTIFIER_KIND);
        bool fkos = (k >= 4 && k <= 6);
        unsigned long long mid  = __ballot(fid);
        unsigned long long mkos = __ballot(fkos);
        if (lane == 0) { swid[wave] = __popcll(mid); swkos[wave] = __popcll(mkos); }
        __syncthreads();
        int bid = 0, bkos = 0, tot_id = 0, tot_kos = 0;
        #pragma unroll
        for (int w = 0; w < 16; ++w) {
            int a = swid[w], b = swkos[w];
            if (w < wave) { bid += a; bkos += b; }
            tot_id += a; tot_kos += b;
        }
        unsigned long long below = (1ull << lane) - 1ull;
        int s = -1;
        if (fid)       s = id_idx[run_id + bid + __popcll(mid & below)];
        else if (fkos) s = NUM_IDS + kos_idx[run_kos + bkos + __popcll(mkos & below)];
        sel[idx] = s;
        run_id += tot_id; run_kos += tot_kos;
        __syncthreads();
    }
}

// ---------------- Kernel 2: prep = W2 transpose->bf16 (blocks 0..255) + kindc (block 256) ----
__global__ __launch_bounds__(256) void prep_kernel(const float* __restrict__ W2,
                                                   const float* __restrict__ kind_emb,
                                                   const float* __restrict__ Wp,
                                                   const float* __restrict__ bp,
                                                   u16* __restrict__ Wt,
                                                   float* __restrict__ kindc) {
    if (blockIdx.x == 256) {
        #pragma unroll
        for (int rep = 0; rep < 2; ++rep) {
            int j = threadIdx.x + rep * 256;
            float bias = bp[j];
            for (int kind = 0; kind < 8; ++kind) {
                float a = bias;
                #pragma unroll
                for (int d = 0; d < KIND_D; ++d)
                    a = fmaf(kind_emb[kind * KIND_D + d], Wp[d * EXPR_D + j], a);
                kindc[kind * EXPR_D + j] = a;
            }
        }
        return;
    }
    __shared__ float tile[32][33];
    const int n0 = (blockIdx.x & 15) * 32;
    const int k0 = (blockIdx.x >> 4) * 32;
    const int t = threadIdx.x;
    const int lj = t & 31, li = t >> 5;   // li 0..7
    #pragma unroll
    for (int p = 0; p < 4; ++p) {
        int i = li + p * 8;
        tile[i][lj] = W2[(size_t)(k0 + i) * EXPR_D + n0 + lj];
    }
    __syncthreads();
    #pragma unroll
    for (int p = 0; p < 4; ++p) {
        int j = li + p * 8;
        Wt[(size_t)(n0 + j) * EXPR_D + k0 + lj] = bf16bits(tile[lj][j]);
    }
}

// ---------------- Kernel 3: P = [enc_ids; kos_emb] @ W_proj[8:,:] (fp32) ----
__global__ __launch_bounds__(256) void proj_kernel(const float* __restrict__ enc_ids,
                                                   const float* __restrict__ kos_emb,
                                                   const float* __restrict__ Wp,
                                                   float* __restrict__ P) {
    __shared__ float xs[TR][DD];   // 32 KiB
    const int row0 = blockIdx.x * TR;
    const int t = threadIdx.x;
    for (int r = 0; r < TR; ++r) {
        int row = row0 + r;
        const float* src = (row < NUM_IDS) ? &enc_ids[(size_t)row * DD]
                                           : &kos_emb[(size_t)(row - NUM_IDS) * DD];
        xs[r][t] = src[t];
    }
    __syncthreads();
    const int tcol = t & 63, trow = t >> 6;
    const int c0 = tcol * 8, r0 = trow * 8;
    const float* W1p = Wp + (size_t)KIND_D * EXPR_D;
    float acc[8][8] = {};
    for (int k = 0; k < DD; k += 4) {
        float4 hv[8];
        #pragma unroll
        for (int r = 0; r < 8; ++r) hv[r] = *(const float4*)&xs[r0 + r][k];
        #pragma unroll
        for (int kk = 0; kk < 4; ++kk) {
            float4 w0 = *(const float4*)&W1p[(size_t)(k + kk) * EXPR_D + c0];
            float4 w1 = *(const float4*)&W1p[(size_t)(k + kk) * EXPR_D + c0 + 4];
            float wc[8] = {w0.x, w0.y, w0.z, w0.w, w1.x, w1.y, w1.z, w1.w};
            #pragma unroll
            for (int r = 0; r < 8; ++r) {
                float hr = (kk == 0) ? hv[r].x : (kk == 1) ? hv[r].y : (kk == 2) ? hv[r].z : hv[r].w;
                #pragma unroll
                for (int c = 0; c < 8; ++c) acc[r][c] = fmaf(hr, wc[c], acc[r][c]);
            }
        }
    }
    #pragma unroll
    for (int r = 0; r < 8; ++r) {
        float* dst = &P[(size_t)(row0 + r0 + r) * EXPR_D + c0];
        *(float4*)&dst[0] = make_float4(acc[r][0], acc[r][1], acc[r][2], acc[r][3]);
        *(float4*)&dst[4] = make_float4(acc[r][4], acc[r][5], acc[r][6], acc[r][7]);
    }
}

// ---------------- Kernel 4: fused gather + layer1 + 2-term split-bf16 MFMA layer2 ----
// BM=128, BN=256, BK=64, 512 threads (8 waves, 2M x 4N), double-buffered LDS,
// T14 async-stage (issue loads early, split+write after MFMA), one barrier/chunk.
__global__ __launch_bounds__(512, 2) void mlp2_kernel(const int* __restrict__ token_type,
                                                      const int* __restrict__ sel,
                                                      const float* __restrict__ P,
                                                      const float* __restrict__ kindc,
                                                      const u16* __restrict__ Wt,
                                                      const float* __restrict__ b2,
                                                      float* __restrict__ out) {
    __shared__ u16 sAhi[2][128 * 64];   // 16 KiB each buf
    __shared__ u16 sAlo[2][128 * 64];
    __shared__ u16 sB[2][256 * 64];     // 32 KiB each buf   -> 128 KiB total

    const int t = threadIdx.x;
    const int row0 = blockIdx.x * 128;
    const int col0 = blockIdx.y * 256;

    // A staging: thread -> row ar, 16 k starting at ac
    const int ar = t >> 2;
    const int ac = (t & 3) * 16;
    // B staging: thread -> row br, 32 k starting at bc
    const int br = t >> 1;
    const int bc = (t & 1) * 32;

    const int g    = sel[row0 + ar];
    const int kind = token_type[row0 + ar];
    const float* Prow = &P[(size_t)(g >= 0 ? g : 0) * EXPR_D];
    const float* Krow = &kindc[kind * EXPR_D];
    const u16*   Brow = &Wt[(size_t)(col0 + br) * EXPR_D];

    const int lane = t & 63;
    const int wid  = t >> 6;
    const int wr = wid >> 2, wc = wid & 3;     // 2x4 wave grid -> 64x64 per wave
    const int lrow = lane & 15, lkg = lane >> 4;

    f32x4 acc[4][4];
    #pragma unroll
    for (int mi = 0; mi < 4; ++mi)
        #pragma unroll
        for (int ni = 0; ni < 4; ++ni)
            acc[mi][ni] = (f32x4){0.f, 0.f, 0.f, 0.f};

    f32x4 ka[4], pa[4];
    u16x8 bv[4];

    auto STAGE_ISSUE = [&](int kc) {
        const int kb = kc * 64;
        #pragma unroll
        for (int j = 0; j < 4; ++j) ka[j] = *(const f32x4*)&Krow[kb + ac + j * 4];
        if (g >= 0) {
            #pragma unroll
            for (int j = 0; j < 4; ++j) pa[j] = *(const f32x4*)&Prow[kb + ac + j * 4];
        }
        #pragma unroll
        for (int j = 0; j < 4; ++j) bv[j] = *(const u16x8*)&Brow[kb + bc + j * 8];
    };

    auto WRITE = [&](int buf) {
        u16 hi[16], lo[16];
        #pragma unroll
        for (int j = 0; j < 4; ++j) {
            f32x4 v = ka[j];
            if (g >= 0) v += pa[j];
            #pragma unroll
            for (int e = 0; e < 4; ++e) {
                float r = fmaxf(v[e], 0.f);
                u16 h = bf16bits(r);
                hi[j * 4 + e] = h;
                lo[j * 4 + e] = bf16bits(r - bf16tof(h));
            }
        }
        const int abase = ar * 128;
        const int o0 = abase + ((ac * 2) ^ ((ar & 7) << 4));
        const int o1 = abase + ((ac * 2 + 16) ^ ((ar & 7) << 4));
        *(u16x8*)((char*)sAhi[buf] + o0) = *(const u16x8*)&hi[0];
        *(u16x8*)((char*)sAhi[buf] + o1) = *(const u16x8*)&hi[8];
        *(u16x8*)((char*)sAlo[buf] + o0) = *(const u16x8*)&lo[0];
        *(u16x8*)((char*)sAlo[buf] + o1) = *(const u16x8*)&lo[8];
        const int bbase = br * 128;
        #pragma unroll
        for (int j = 0; j < 4; ++j) {
            int off = bbase + ((bc * 2 + j * 16) ^ ((br & 7) << 4));
            *(u16x8*)((char*)sB[buf] + off) = bv[j];
        }
    };

    auto COMPUTE = [&](int buf) {
        #pragma unroll
        for (int ks = 0; ks < 2; ++ks) {
            s16x8 ah[4], al[4], bbf[4];
            #pragma unroll
            for (int mi = 0; mi < 4; ++mi) {
                int row = wr * 64 + mi * 16 + lrow;
                int off = row * 128 + ((ks * 64 + lkg * 16) ^ ((row & 7) << 4));
                ah[mi] = *(const s16x8*)((const char*)sAhi[buf] + off);
                al[mi] = *(const s16x8*)((const char*)sAlo[buf] + off);
            }
            #pragma unroll
            for (int ni = 0; ni < 4; ++ni) {
                int row = wc * 64 + ni * 16 + lrow;
                int off = row * 128 + ((ks * 64 + lkg * 16) ^ ((row & 7) << 4));
                bbf[ni] = *(const s16x8*)((const char*)sB[buf] + off);
            }
            #pragma unroll
            for (int mi = 0; mi < 4; ++mi)
                #pragma unroll
                for (int ni = 0; ni < 4; ++ni) {
                    acc[mi][ni] = __builtin_amdgcn_mfma_f32_16x16x32_bf16(ah[mi], bbf[ni], acc[mi][ni], 0, 0, 0);
                    acc[mi][ni] = __builtin_amdgcn_mfma_f32_16x16x32_bf16(al[mi], bbf[ni], acc[mi][ni], 0, 0, 0);
                }
        }
    };

    STAGE_ISSUE(0);
    WRITE(0);
    __syncthreads();
    int cur = 0;
    #pragma unroll 1
    for (int kc = 0; kc < 8; ++kc) {
        if (kc < 7) STAGE_ISSUE(kc + 1);
        COMPUTE(cur);
        if (kc < 7) WRITE(cur ^ 1);
        __syncthreads();
        cur ^= 1;
    }

    // epilogue: bias + relu; C/D map col=lane&15, row=(lane>>4)*4+reg
    #pragma unroll
    for (int ni = 0; ni < 4; ++ni) {
        int col = col0 + wc * 64 + ni * 16 + lrow;
        float bias = b2[col];
        #pragma unroll
        for (int mi = 0; mi < 4; ++mi) {
            int rbase = row0 + wr * 64 + mi * 16 + lkg * 4;
            #pragma unroll
            for (int j = 0; j < 4; ++j)
                out[(size_t)(rbase + j) * EXPR_D + col] = fmaxf(acc[mi][ni][j] + bias, 0.f);
        }
    }
}

extern "C" void kernel_launch(void* const* d_in, const int* in_sizes, int n_in,
                              void* d_out, int out_size, void* d_ws, size_t ws_size,
                              hipStream_t stream) {
    const int*   token_type = (const int*)d_in[0];
    const int*   kos_idx    = (const int*)d_in[1];
    const int*   id_idx     = (const int*)d_in[2];
    const float* enc_ids    = (const float*)d_in[3];
    const float* kind_emb   = (const float*)d_in[4];
    const float* kos_emb    = (const float*)d_in[5];
    const float* Wp         = (const float*)d_in[6];
    const float* bp         = (const float*)d_in[7];
    const float* W2         = (const float*)d_in[8];
    const float* b2         = (const float*)d_in[9];
    float* out = (float*)d_out;

    char* ws = (char*)d_ws;
    int*   sel   = (int*)ws;                                   // 256 KiB
    float* kindc = (float*)(ws + 262144);                      // 16 KiB
    float* P     = (float*)(ws + 262144 + 16384);              // 17.3 MiB
    u16*   Wt    = (u16*)(ws + 262144 + 16384 + (size_t)(NUM_IDS + KOS_VOCAB) * EXPR_D * 4);

    hipLaunchKernelGGL(scan_kernel, dim3(1), dim3(1024), 0, stream,
                       token_type, kos_idx, id_idx, sel);
    hipLaunchKernelGGL(prep_kernel, dim3(257), dim3(256), 0, stream,
                       W2, kind_emb, Wp, bp, Wt, kindc);
    hipLaunchKernelGGL(proj_kernel, dim3((NUM_IDS + KOS_VOCAB) / TR), dim3(256), 0, stream,
                       enc_ids, kos_emb, Wp, P);
    hipLaunchKernelGGL(mlp2_kernel, dim3(NPOS / 128, EXPR_D / 256), dim3(512), 0, stream,
                       token_type, sel, P, kindc, Wt, b2, out);
}

// Round 4
// 106.745 us; speedup vs baseline: 5.5379x; 2.2010x over previous
//
#include <hip/hip_runtime.h>
#include <hip/hip_bf16.h>

#define BB 128
#define SS 512
#define NPOS (BB*SS)          // 65536
#define DD 256
#define KIND_D 8
#define EXPR_D 512
#define KOS_VOCAB 256
#define NUM_IDS 8192
#define IDENTIFIER_KIND 3

typedef unsigned short u16;
typedef __attribute__((ext_vector_type(8))) short s16x8;           // 8 bf16 (4 VGPRs)
typedef __attribute__((ext_vector_type(8))) unsigned short u16x8;  // 16B store unit
typedef __attribute__((ext_vector_type(4))) float f32x4;

__device__ __forceinline__ u16 bf16bits(float v) {
    __hip_bfloat16 h = __float2bfloat16(v);
    return *(u16*)&h;
}
__device__ __forceinline__ float bf16tof(u16 b) {
    __hip_bfloat16 h = *(__hip_bfloat16*)&b;
    return __bfloat162float(h);
}

// ---------------- Kernel 1: prep ----------------
// blocks 0..255   : W2 [512k][512n] f32 -> Wt [n][k] bf16
// block  256      : kindc[kind][j] = kind_emb[kind] @ W_proj[0:8] + b_proj
// blocks 257..384 : W_proj[8:264] [256k][512n] f32 -> Wt1 [n][k] bf16
// blocks 385..640 : per-256-chunk {id,kos} counts of token_type -> blkcnt
__global__ __launch_bounds__(256) void prep_kernel(const float* __restrict__ W2,
                                                   const float* __restrict__ kind_emb,
                                                   const float* __restrict__ Wp,
                                                   const float* __restrict__ bp,
                                                   const int* __restrict__ token_type,
                                                   u16* __restrict__ Wt,
                                                   u16* __restrict__ Wt1,
                                                   float* __restrict__ kindc,
                                                   int2* __restrict__ blkcnt) {
    __shared__ float tile[32][33];
    __shared__ int swid[4], swkos[4];
    const int bi = blockIdx.x;
    const int t = threadIdx.x;

    if (bi < 256) {                       // W2 transpose -> bf16
        const int n0 = (bi & 15) * 32;
        const int k0 = (bi >> 4) * 32;
        const int lj = t & 31, li = t >> 5;
        #pragma unroll
        for (int p = 0; p < 4; ++p) {
            int i = li + p * 8;
            tile[i][lj] = W2[(size_t)(k0 + i) * EXPR_D + n0 + lj];
        }
        __syncthreads();
        #pragma unroll
        for (int p = 0; p < 4; ++p) {
            int j = li + p * 8;
            Wt[(size_t)(n0 + j) * EXPR_D + k0 + lj] = bf16bits(tile[lj][j]);
        }
    } else if (bi == 256) {               // kindc
        #pragma unroll
        for (int rep = 0; rep < 2; ++rep) {
            int j = t + rep * 256;
            float bias = bp[j];
            for (int kind = 0; kind < 8; ++kind) {
                float a = bias;
                #pragma unroll
                for (int d = 0; d < KIND_D; ++d)
                    a = fmaf(kind_emb[kind * KIND_D + d], Wp[d * EXPR_D + j], a);
                kindc[kind * EXPR_D + j] = a;
            }
        }
    } else if (bi < 385) {                // W1 transpose -> bf16
        const int idx = bi - 257;
        const int n0 = (idx & 15) * 32;
        const int k0 = (idx >> 4) * 32;
        const float* W1p = Wp + (size_t)KIND_D * EXPR_D;
        const int lj = t & 31, li = t >> 5;
        #pragma unroll
        for (int p = 0; p < 4; ++p) {
            int i = li + p * 8;
            tile[i][lj] = W1p[(size_t)(k0 + i) * EXPR_D + n0 + lj];
        }
        __syncthreads();
        #pragma unroll
        for (int p = 0; p < 4; ++p) {
            int j = li + p * 8;
            Wt1[(size_t)(n0 + j) * DD + k0 + lj] = bf16bits(tile[lj][j]);
        }
    } else {                              // count chunk of 256 positions
        const int blk = bi - 385;
        const int lane = t & 63, wave = t >> 6;
        int k = token_type[blk * 256 + t];
        unsigned long long mid  = __ballot(k == IDENTIFIER_KIND);
        unsigned long long mkos = __ballot(k >= 4 && k <= 6);
        if (lane == 0) { swid[wave] = __popcll(mid); swkos[wave] = __popcll(mkos); }
        __syncthreads();
        if (t == 0) {
            int a = 0, c = 0;
            #pragma unroll
            for (int w = 0; w < 4; ++w) { a += swid[w]; c += swkos[w]; }
            blkcnt[blk] = make_int2(a, c);
        }
    }
}

// ---------------- Kernel 2: scatter -> sel[] ----------------
// 256 blocks x 256 threads; each block prefixes blkcnt[0..b) then ballot-ranks.
__global__ __launch_bounds__(256) void scatter_kernel(const int* __restrict__ token_type,
                                                      const int2* __restrict__ blkcnt,
                                                      const int* __restrict__ kos_idx,
                                                      const int* __restrict__ id_idx,
                                                      int* __restrict__ sel) {
    __shared__ int2 sbase;
    __shared__ int swid[4], swkos[4];
    const int b = blockIdx.x, t = threadIdx.x;
    const int lane = t & 63, wave = t >> 6;
    if (t < 64) {
        int a = 0, c = 0;
        for (int i = t; i < b; i += 64) { int2 v = blkcnt[i]; a += v.x; c += v.y; }
        #pragma unroll
        for (int off = 32; off; off >>= 1) { a += __shfl_down(a, off); c += __shfl_down(c, off); }
        if (t == 0) sbase = make_int2(a, c);
    }
    const int idx = b * 256 + t;
    const int k = token_type[idx];
    const bool fid  = (k == IDENTIFIER_KIND);
    const bool fkos = (k >= 4 && k <= 6);
    unsigned long long mid  = __ballot(fid);
    unsigned long long mkos = __ballot(fkos);
    if (lane == 0) { swid[wave] = __popcll(mid); swkos[wave] = __popcll(mkos); }
    __syncthreads();
    int bid = 0, bkos = 0;
    for (int w = 0; w < wave; ++w) { bid += swid[w]; bkos += swkos[w]; }
    unsigned long long below = (1ull << lane) - 1ull;
    int s = -1;
    if (fid)       s = id_idx[sbase.x + bid + __popcll(mid & below)];
    else if (fkos) s = NUM_IDS + kos_idx[sbase.y + bkos + __popcll(mkos & below)];
    sel[idx] = s;
}

// ---------------- Kernel 3: P = [enc_ids; kos_emb] @ W1 via 2-term split-bf16 MFMA ----
// BM=128, BN=256, BK=64, K=256 (4 chunks), 512 threads (2x4 waves), dbuf LDS.
__global__ __launch_bounds__(512, 2) void projmm_kernel(const float* __restrict__ enc_ids,
                                                        const float* __restrict__ kos_emb,
                                                        const u16* __restrict__ Wt1,
                                                        float* __restrict__ P) {
    __shared__ u16 sAhi[2][128 * 64];
    __shared__ u16 sAlo[2][128 * 64];
    __shared__ u16 sB[2][256 * 64];

    const int t = threadIdx.x;
    const int row0 = blockIdx.x * 128;
    const int col0 = blockIdx.y * 256;

    const int ar = t >> 2;
    const int ac = (t & 3) * 16;
    const int br = t >> 1;
    const int bc = (t & 1) * 32;

    const int arow = row0 + ar;
    const float* Arow = (arow < NUM_IDS) ? &enc_ids[(size_t)arow * DD]
                                         : &kos_emb[(size_t)(arow - NUM_IDS) * DD];
    const u16* Brow = &Wt1[(size_t)(col0 + br) * DD];

    const int lane = t & 63;
    const int wid  = t >> 6;
    const int wr = wid >> 2, wc = wid & 3;
    const int lrow = lane & 15, lkg = lane >> 4;

    f32x4 acc[4][4];
    #pragma unroll
    for (int mi = 0; mi < 4; ++mi)
        #pragma unroll
        for (int ni = 0; ni < 4; ++ni)
            acc[mi][ni] = (f32x4){0.f, 0.f, 0.f, 0.f};

    f32x4 av[4];
    u16x8 bv[4];

    auto STAGE_ISSUE = [&](int kc) {
        const int kb = kc * 64;
        #pragma unroll
        for (int j = 0; j < 4; ++j) av[j] = *(const f32x4*)&Arow[kb + ac + j * 4];
        #pragma unroll
        for (int j = 0; j < 4; ++j) bv[j] = *(const u16x8*)&Brow[kb + bc + j * 8];
    };

    auto WRITE = [&](int buf) {
        u16 hi[16], lo[16];
        #pragma unroll
        for (int j = 0; j < 4; ++j) {
            #pragma unroll
            for (int e = 0; e < 4; ++e) {
                float r = av[j][e];
                u16 h = bf16bits(r);
                hi[j * 4 + e] = h;
                lo[j * 4 + e] = bf16bits(r - bf16tof(h));
            }
        }
        const int abase = ar * 128;
        const int o0 = abase + ((ac * 2) ^ ((ar & 7) << 4));
        const int o1 = abase + ((ac * 2 + 16) ^ ((ar & 7) << 4));
        *(u16x8*)((char*)sAhi[buf] + o0) = *(const u16x8*)&hi[0];
        *(u16x8*)((char*)sAhi[buf] + o1) = *(const u16x8*)&hi[8];
        *(u16x8*)((char*)sAlo[buf] + o0) = *(const u16x8*)&lo[0];
        *(u16x8*)((char*)sAlo[buf] + o1) = *(const u16x8*)&lo[8];
        const int bbase = br * 128;
        #pragma unroll
        for (int j = 0; j < 4; ++j) {
            int off = bbase + ((bc * 2 + j * 16) ^ ((br & 7) << 4));
            *(u16x8*)((char*)sB[buf] + off) = bv[j];
        }
    };

    auto COMPUTE = [&](int buf) {
        #pragma unroll
        for (int ks = 0; ks < 2; ++ks) {
            s16x8 ah[4], al[4], bbf[4];
            #pragma unroll
            for (int mi = 0; mi < 4; ++mi) {
                int row = wr * 64 + mi * 16 + lrow;
                int off = row * 128 + ((ks * 64 + lkg * 16) ^ ((row & 7) << 4));
                ah[mi] = *(const s16x8*)((const char*)sAhi[buf] + off);
                al[mi] = *(const s16x8*)((const char*)sAlo[buf] + off);
            }
            #pragma unroll
            for (int ni = 0; ni < 4; ++ni) {
                int row = wc * 64 + ni * 16 + lrow;
                int off = row * 128 + ((ks * 64 + lkg * 16) ^ ((row & 7) << 4));
                bbf[ni] = *(const s16x8*)((const char*)sB[buf] + off);
            }
            #pragma unroll
            for (int mi = 0; mi < 4; ++mi)
                #pragma unroll
                for (int ni = 0; ni < 4; ++ni) {
                    acc[mi][ni] = __builtin_amdgcn_mfma_f32_16x16x32_bf16(ah[mi], bbf[ni], acc[mi][ni], 0, 0, 0);
                    acc[mi][ni] = __builtin_amdgcn_mfma_f32_16x16x32_bf16(al[mi], bbf[ni], acc[mi][ni], 0, 0, 0);
                }
        }
    };

    STAGE_ISSUE(0);
    WRITE(0);
    __syncthreads();
    int cur = 0;
    #pragma unroll 1
    for (int kc = 0; kc < 4; ++kc) {
        if (kc < 3) STAGE_ISSUE(kc + 1);
        COMPUTE(cur);
        if (kc < 3) WRITE(cur ^ 1);
        __syncthreads();
        cur ^= 1;
    }

    #pragma unroll
    for (int ni = 0; ni < 4; ++ni) {
        int col = col0 + wc * 64 + ni * 16 + lrow;
        #pragma unroll
        for (int mi = 0; mi < 4; ++mi) {
            int rbase = row0 + wr * 64 + mi * 16 + lkg * 4;
            #pragma unroll
            for (int j = 0; j < 4; ++j)
                P[(size_t)(rbase + j) * EXPR_D + col] = acc[mi][ni][j];
        }
    }
}

// ---------------- Kernel 4: fused gather + layer1 + 2-term split-bf16 MFMA layer2 ----
__global__ __launch_bounds__(512, 2) void mlp2_kernel(const int* __restrict__ token_type,
                                                      const int* __restrict__ sel,
                                                      const float* __restrict__ P,
                                                      const float* __restrict__ kindc,
                                                      const u16* __restrict__ Wt,
                                                      const float* __restrict__ b2,
                                                      float* __restrict__ out) {
    __shared__ u16 sAhi[2][128 * 64];
    __shared__ u16 sAlo[2][128 * 64];
    __shared__ u16 sB[2][256 * 64];

    const int t = threadIdx.x;
    const int row0 = blockIdx.x * 128;
    const int col0 = blockIdx.y * 256;

    const int ar = t >> 2;
    const int ac = (t & 3) * 16;
    const int br = t >> 1;
    const int bc = (t & 1) * 32;

    const int g    = sel[row0 + ar];
    const int kind = token_type[row0 + ar];
    const float* Prow = &P[(size_t)(g >= 0 ? g : 0) * EXPR_D];
    const float* Krow = &kindc[kind * EXPR_D];
    const u16*   Brow = &Wt[(size_t)(col0 + br) * EXPR_D];

    const int lane = t & 63;
    const int wid  = t >> 6;
    const int wr = wid >> 2, wc = wid & 3;
    const int lrow = lane & 15, lkg = lane >> 4;

    f32x4 acc[4][4];
    #pragma unroll
    for (int mi = 0; mi < 4; ++mi)
        #pragma unroll
        for (int ni = 0; ni < 4; ++ni)
            acc[mi][ni] = (f32x4){0.f, 0.f, 0.f, 0.f};

    f32x4 ka[4], pa[4];
    u16x8 bv[4];

    auto STAGE_ISSUE = [&](int kc) {
        const int kb = kc * 64;
        #pragma unroll
        for (int j = 0; j < 4; ++j) ka[j] = *(const f32x4*)&Krow[kb + ac + j * 4];
        if (g >= 0) {
            #pragma unroll
            for (int j = 0; j < 4; ++j) pa[j] = *(const f32x4*)&Prow[kb + ac + j * 4];
        }
        #pragma unroll
        for (int j = 0; j < 4; ++j) bv[j] = *(const u16x8*)&Brow[kb + bc + j * 8];
    };

    auto WRITE = [&](int buf) {
        u16 hi[16], lo[16];
        #pragma unroll
        for (int j = 0; j < 4; ++j) {
            f32x4 v = ka[j];
            if (g >= 0) v += pa[j];
            #pragma unroll
            for (int e = 0; e < 4; ++e) {
                float r = fmaxf(v[e], 0.f);
                u16 h = bf16bits(r);
                hi[j * 4 + e] = h;
                lo[j * 4 + e] = bf16bits(r - bf16tof(h));
            }
        }
        const int abase = ar * 128;
        const int o0 = abase + ((ac * 2) ^ ((ar & 7) << 4));
        const int o1 = abase + ((ac * 2 + 16) ^ ((ar & 7) << 4));
        *(u16x8*)((char*)sAhi[buf] + o0) = *(const u16x8*)&hi[0];
        *(u16x8*)((char*)sAhi[buf] + o1) = *(const u16x8*)&hi[8];
        *(u16x8*)((char*)sAlo[buf] + o0) = *(const u16x8*)&lo[0];
        *(u16x8*)((char*)sAlo[buf] + o1) = *(const u16x8*)&lo[8];
        const int bbase = br * 128;
        #pragma unroll
        for (int j = 0; j < 4; ++j) {
            int off = bbase + ((bc * 2 + j * 16) ^ ((br & 7) << 4));
            *(u16x8*)((char*)sB[buf] + off) = bv[j];
        }
    };

    auto COMPUTE = [&](int buf) {
        #pragma unroll
        for (int ks = 0; ks < 2; ++ks) {
            s16x8 ah[4], al[4], bbf[4];
            #pragma unroll
            for (int mi = 0; mi < 4; ++mi) {
                int row = wr * 64 + mi * 16 + lrow;
                int off = row * 128 + ((ks * 64 + lkg * 16) ^ ((row & 7) << 4));
                ah[mi] = *(const s16x8*)((const char*)sAhi[buf] + off);
                al[mi] = *(const s16x8*)((const char*)sAlo[buf] + off);
            }
            #pragma unroll
            for (int ni = 0; ni < 4; ++ni) {
                int row = wc * 64 + ni * 16 + lrow;
                int off = row * 128 + ((ks * 64 + lkg * 16) ^ ((row & 7) << 4));
                bbf[ni] = *(const s16x8*)((const char*)sB[buf] + off);
            }
            #pragma unroll
            for (int mi = 0; mi < 4; ++mi)
                #pragma unroll
                for (int ni = 0; ni < 4; ++ni) {
                    acc[mi][ni] = __builtin_amdgcn_mfma_f32_16x16x32_bf16(ah[mi], bbf[ni], acc[mi][ni], 0, 0, 0);
                    acc[mi][ni] = __builtin_amdgcn_mfma_f32_16x16x32_bf16(al[mi], bbf[ni], acc[mi][ni], 0, 0, 0);
                }
        }
    };

    STAGE_ISSUE(0);
    WRITE(0);
    __syncthreads();
    int cur = 0;
    #pragma unroll 1
    for (int kc = 0; kc < 8; ++kc) {
        if (kc < 7) STAGE_ISSUE(kc + 1);
        COMPUTE(cur);
        if (kc < 7) WRITE(cur ^ 1);
        __syncthreads();
        cur ^= 1;
    }

    #pragma unroll
    for (int ni = 0; ni < 4; ++ni) {
        int col = col0 + wc * 64 + ni * 16 + lrow;
        float bias = b2[col];
        #pragma unroll
        for (int mi = 0; mi < 4; ++mi) {
            int rbase = row0 + wr * 64 + mi * 16 + lkg * 4;
            #pragma unroll
            for (int j = 0; j < 4; ++j)
                out[(size_t)(rbase + j) * EXPR_D + col] = fmaxf(acc[mi][ni][j] + bias, 0.f);
        }
    }
}

extern "C" void kernel_launch(void* const* d_in, const int* in_sizes, int n_in,
                              void* d_out, int out_size, void* d_ws, size_t ws_size,
                              hipStream_t stream) {
    const int*   token_type = (const int*)d_in[0];
    const int*   kos_idx    = (const int*)d_in[1];
    const int*   id_idx     = (const int*)d_in[2];
    const float* enc_ids    = (const float*)d_in[3];
    const float* kind_emb   = (const float*)d_in[4];
    const float* kos_emb    = (const float*)d_in[5];
    const float* Wp         = (const float*)d_in[6];
    const float* bp         = (const float*)d_in[7];
    const float* W2         = (const float*)d_in[8];
    const float* b2         = (const float*)d_in[9];
    float* out = (float*)d_out;

    char* ws = (char*)d_ws;
    int*   sel    = (int*)ws;                                  // 256 KiB
    float* kindc  = (float*)(ws + 262144);                     // 16 KiB
    float* P      = (float*)(ws + 278528);                     // 17.3 MiB
    u16*   Wt     = (u16*)(ws + 17580032);                     // 512 KiB (W2^T bf16)
    u16*   Wt1    = (u16*)(ws + 18104320);                     // 256 KiB (W1^T bf16)
    int2*  blkcnt = (int2*)(ws + 18366464);                    // 2 KiB

    hipLaunchKernelGGL(prep_kernel, dim3(641), dim3(256), 0, stream,
                       W2, kind_emb, Wp, bp, token_type, Wt, Wt1, kindc, blkcnt);
    hipLaunchKernelGGL(scatter_kernel, dim3(256), dim3(256), 0, stream,
                       token_type, blkcnt, kos_idx, id_idx, sel);
    hipLaunchKernelGGL(projmm_kernel, dim3((NUM_IDS + KOS_VOCAB) / 128, EXPR_D / 256), dim3(512), 0, stream,
                       enc_ids, kos_emb, Wt1, P);
    hipLaunchKernelGGL(mlp2_kernel, dim3(NPOS / 128, EXPR_D / 256), dim3(512), 0, stream,
                       token_type, sel, P, kindc, Wt, b2, out);
}

// Round 5
// 82.354 us; speedup vs baseline: 7.1781x; 1.2962x over previous
//
#include <hip/hip_runtime.h>
#include <hip/hip_bf16.h>

#define BB 128
#define SS 512
#define NPOS (BB*SS)          // 65536
#define DD 256
#define KIND_D 8
#define EXPR_D 512
#define KOS_VOCAB 256
#define NUM_IDS 8192
#define IDENTIFIER_KIND 3
#define TROWS 9088            // padded table rows (8968 used)

typedef unsigned short u16;
typedef __attribute__((ext_vector_type(8))) short s16x8;           // 8 bf16 (4 VGPRs)
typedef __attribute__((ext_vector_type(8))) unsigned short u16x8;  // 16B unit
typedef __attribute__((ext_vector_type(4))) float f32x4;

__device__ __forceinline__ u16 bf16bits(float v) {
    __hip_bfloat16 h = __float2bfloat16(v);
    return *(u16*)&h;
}
__device__ __forceinline__ float bf16tof(u16 b) {
    __hip_bfloat16 h = *(__hip_bfloat16*)&b;
    return __bfloat162float(h);
}

// ---------------- Kernel 1: prep ----------------
// blocks 0..255   : W2 [512k][512n] f32 -> Wt [n][k] bf16
// block  256      : kindc[kind][j] = kind_emb[kind] @ W_proj[0:8] + b_proj
// blocks 257..384 : W_proj[8:264] [256k][512n] f32 -> Wt1 [n][k] bf16
// blocks 385..640 : per-256-chunk {id,kos} counts of token_type -> blkcnt
__global__ __launch_bounds__(256) void prep_kernel(const float* __restrict__ W2,
                                                   const float* __restrict__ kind_emb,
                                                   const float* __restrict__ Wp,
                                                   const float* __restrict__ bp,
                                                   const int* __restrict__ token_type,
                                                   u16* __restrict__ Wt,
                                                   u16* __restrict__ Wt1,
                                                   float* __restrict__ kindc,
                                                   int2* __restrict__ blkcnt) {
    __shared__ float tile[32][33];
    __shared__ int swid[4], swkos[4];
    const int bi = blockIdx.x;
    const int t = threadIdx.x;

    if (bi < 256) {
        const int n0 = (bi & 15) * 32;
        const int k0 = (bi >> 4) * 32;
        const int lj = t & 31, li = t >> 5;
        #pragma unroll
        for (int p = 0; p < 4; ++p) {
            int i = li + p * 8;
            tile[i][lj] = W2[(size_t)(k0 + i) * EXPR_D + n0 + lj];
        }
        __syncthreads();
        #pragma unroll
        for (int p = 0; p < 4; ++p) {
            int j = li + p * 8;
            Wt[(size_t)(n0 + j) * EXPR_D + k0 + lj] = bf16bits(tile[lj][j]);
        }
    } else if (bi == 256) {
        #pragma unroll
        for (int rep = 0; rep < 2; ++rep) {
            int j = t + rep * 256;
            float bias = bp[j];
            for (int kind = 0; kind < 8; ++kind) {
                float a = bias;
                #pragma unroll
                for (int d = 0; d < KIND_D; ++d)
                    a = fmaf(kind_emb[kind * KIND_D + d], Wp[d * EXPR_D + j], a);
                kindc[kind * EXPR_D + j] = a;
            }
        }
    } else if (bi < 385) {
        const int idx = bi - 257;
        const int n0 = (idx & 15) * 32;
        const int k0 = (idx >> 4) * 32;
        const float* W1p = Wp + (size_t)KIND_D * EXPR_D;
        const int lj = t & 31, li = t >> 5;
        #pragma unroll
        for (int p = 0; p < 4; ++p) {
            int i = li + p * 8;
            tile[i][lj] = W1p[(size_t)(k0 + i) * EXPR_D + n0 + lj];
        }
        __syncthreads();
        #pragma unroll
        for (int p = 0; p < 4; ++p) {
            int j = li + p * 8;
            Wt1[(size_t)(n0 + j) * DD + k0 + lj] = bf16bits(tile[lj][j]);
        }
    } else {
        const int blk = bi - 385;
        const int lane = t & 63, wave = t >> 6;
        int k = token_type[blk * 256 + t];
        unsigned long long mid  = __ballot(k == IDENTIFIER_KIND);
        unsigned long long mkos = __ballot(k >= 4 && k <= 6);
        if (lane == 0) { swid[wave] = __popcll(mid); swkos[wave] = __popcll(mkos); }
        __syncthreads();
        if (t == 0) {
            int a = 0, c = 0;
            #pragma unroll
            for (int w = 0; w < 4; ++w) { a += swid[w]; c += swkos[w]; }
            blkcnt[blk] = make_int2(a, c);
        }
    }
}

// ---------------- Kernel 2: scatter -> sel2[] (direct table-row index) ----------------
// id rows: 0..8191 ; kos rows: 8192 + (kind-4)*256 + kos_idx ; none: 8960 + kind
__global__ __launch_bounds__(256) void scatter_kernel(const int* __restrict__ token_type,
                                                      const int2* __restrict__ blkcnt,
                                                      const int* __restrict__ kos_idx,
                                                      const int* __restrict__ id_idx,
                                                      int* __restrict__ sel2) {
    __shared__ int2 sbase;
    __shared__ int swid[4], swkos[4];
    const int b = blockIdx.x, t = threadIdx.x;
    const int lane = t & 63, wave = t >> 6;
    if (t < 64) {
        int a = 0, c = 0;
        for (int i = t; i < b; i += 64) { int2 v = blkcnt[i]; a += v.x; c += v.y; }
        #pragma unroll
        for (int off = 32; off; off >>= 1) { a += __shfl_down(a, off); c += __shfl_down(c, off); }
        if (t == 0) sbase = make_int2(a, c);
    }
    const int idx = b * 256 + t;
    const int k = token_type[idx];
    const bool fid  = (k == IDENTIFIER_KIND);
    const bool fkos = (k >= 4 && k <= 6);
    unsigned long long mid  = __ballot(fid);
    unsigned long long mkos = __ballot(fkos);
    if (lane == 0) { swid[wave] = __popcll(mid); swkos[wave] = __popcll(mkos); }
    __syncthreads();
    int bid = 0, bkos = 0;
    for (int w = 0; w < wave; ++w) { bid += swid[w]; bkos += swkos[w]; }
    unsigned long long below = (1ull << lane) - 1ull;
    int s;
    if (fid)       s = id_idx[sbase.x + bid + __popcll(mid & below)];
    else if (fkos) s = 8192 + (k - 4) * 256 + kos_idx[sbase.y + bkos + __popcll(mkos & below)];
    else           s = 8960 + k;
    sel2[idx] = s;
}

// ---------------- Kernel 3: build Thi = bf16(relu(kindc[kind] + x @ W1)) ----------------
// rows: 0..8191 = enc_ids (kind 3); 8192..8959 = kos (kind 4+q>>8); 8960..8967 = zero src.
// BM=128, BN=256, BK=64, K=256 (4 chunks), 512 threads, 2-term split-bf16 MFMA.
__global__ __launch_bounds__(512, 2) void table_kernel(const float* __restrict__ enc_ids,
                                                       const float* __restrict__ kos_emb,
                                                       const u16* __restrict__ Wt1,
                                                       const float* __restrict__ kindc,
                                                       u16* __restrict__ Thi) {
    __shared__ u16 sAhi[2][128 * 64];
    __shared__ u16 sAlo[2][128 * 64];
    __shared__ u16 sB[2][256 * 64];

    const int t = threadIdx.x;
    const int row0 = blockIdx.x * 128;
    const int col0 = blockIdx.y * 256;

    const int ar = t >> 2;
    const int ac = (t & 3) * 16;
    const int br = t >> 1;
    const int bc = (t & 1) * 32;

    const int arow = row0 + ar;
    const float* Arow;
    bool hasrc = true;
    if (arow < NUM_IDS)        Arow = &enc_ids[(size_t)arow * DD];
    else if (arow < 8960)      Arow = &kos_emb[(size_t)((arow - NUM_IDS) & 255) * DD];
    else { Arow = enc_ids; hasrc = false; }
    const u16* Brow = &Wt1[(size_t)(col0 + br) * DD];

    const int lane = t & 63;
    const int wid  = t >> 6;
    const int wr = wid >> 2, wc = wid & 3;
    const int lrow = lane & 15, lkg = lane >> 4;

    f32x4 acc[4][4];
    #pragma unroll
    for (int mi = 0; mi < 4; ++mi)
        #pragma unroll
        for (int ni = 0; ni < 4; ++ni)
            acc[mi][ni] = (f32x4){0.f, 0.f, 0.f, 0.f};

    f32x4 av[4];
    u16x8 bv[4];

    auto STAGE_ISSUE = [&](int kc) {
        const int kb = kc * 64;
        #pragma unroll
        for (int j = 0; j < 4; ++j)
            av[j] = hasrc ? *(const f32x4*)&Arow[kb + ac + j * 4] : (f32x4){0.f,0.f,0.f,0.f};
        #pragma unroll
        for (int j = 0; j < 4; ++j) bv[j] = *(const u16x8*)&Brow[kb + bc + j * 8];
    };

    auto WRITE = [&](int buf) {
        u16 hi[16], lo[16];
        #pragma unroll
        for (int j = 0; j < 4; ++j)
            #pragma unroll
            for (int e = 0; e < 4; ++e) {
                float r = av[j][e];
                u16 h = bf16bits(r);
                hi[j * 4 + e] = h;
                lo[j * 4 + e] = bf16bits(r - bf16tof(h));
            }
        const int abase = ar * 128;
        const int o0 = abase + ((ac * 2) ^ ((ar & 7) << 4));
        const int o1 = abase + ((ac * 2 + 16) ^ ((ar & 7) << 4));
        *(u16x8*)((char*)sAhi[buf] + o0) = *(const u16x8*)&hi[0];
        *(u16x8*)((char*)sAhi[buf] + o1) = *(const u16x8*)&hi[8];
        *(u16x8*)((char*)sAlo[buf] + o0) = *(const u16x8*)&lo[0];
        *(u16x8*)((char*)sAlo[buf] + o1) = *(const u16x8*)&lo[8];
        const int bbase = br * 128;
        #pragma unroll
        for (int j = 0; j < 4; ++j) {
            int off = bbase + ((bc * 2 + j * 16) ^ ((br & 7) << 4));
            *(u16x8*)((char*)sB[buf] + off) = bv[j];
        }
    };

    auto COMPUTE = [&](int buf) {
        #pragma unroll
        for (int ks = 0; ks < 2; ++ks) {
            s16x8 ah[4], al[4], bbf[4];
            #pragma unroll
            for (int mi = 0; mi < 4; ++mi) {
                int row = wr * 64 + mi * 16 + lrow;
                int off = row * 128 + ((ks * 64 + lkg * 16) ^ ((row & 7) << 4));
                ah[mi] = *(const s16x8*)((const char*)sAhi[buf] + off);
                al[mi] = *(const s16x8*)((const char*)sAlo[buf] + off);
            }
            #pragma unroll
            for (int ni = 0; ni < 4; ++ni) {
                int row = wc * 64 + ni * 16 + lrow;
                int off = row * 128 + ((ks * 64 + lkg * 16) ^ ((row & 7) << 4));
                bbf[ni] = *(const s16x8*)((const char*)sB[buf] + off);
            }
            #pragma unroll
            for (int mi = 0; mi < 4; ++mi)
                #pragma unroll
                for (int ni = 0; ni < 4; ++ni) {
                    acc[mi][ni] = __builtin_amdgcn_mfma_f32_16x16x32_bf16(ah[mi], bbf[ni], acc[mi][ni], 0, 0, 0);
                    acc[mi][ni] = __builtin_amdgcn_mfma_f32_16x16x32_bf16(al[mi], bbf[ni], acc[mi][ni], 0, 0, 0);
                }
        }
    };

    STAGE_ISSUE(0);
    WRITE(0);
    __syncthreads();
    int cur = 0;
    #pragma unroll 1
    for (int kc = 0; kc < 4; ++kc) {
        if (kc < 3) STAGE_ISSUE(kc + 1);
        COMPUTE(cur);
        if (kc < 3) WRITE(cur ^ 1);
        __syncthreads();
        cur ^= 1;
    }

    // epilogue: add kindc[kind(row)], relu, bf16, store
    #pragma unroll
    for (int ni = 0; ni < 4; ++ni) {
        int col = col0 + wc * 64 + ni * 16 + lrow;
        #pragma unroll
        for (int mi = 0; mi < 4; ++mi) {
            int rbase = row0 + wr * 64 + mi * 16 + lkg * 4;
            #pragma unroll
            for (int j = 0; j < 4; ++j) {
                int rg = rbase + j;
                int kind = (rg < NUM_IDS) ? 3
                         : (rg < 8960) ? 4 + ((rg - NUM_IDS) >> 8)
                         : (rg < 8968) ? (rg - 8960) : 0;
                float v = acc[mi][ni][j] + kindc[kind * EXPR_D + col];
                Thi[(size_t)rg * EXPR_D + col] = bf16bits(fmaxf(v, 0.f));
            }
        }
    }
}

// ---------------- Kernel 4: out = relu(Thi[sel2] @ Wt^T + b2)  (pure bf16 GEMM) ----------
// BM=128, BN=256, BK=32 (16 chunks), 512 threads (2x4 waves), dbuf LDS = 48 KiB.
__global__ __launch_bounds__(512, 4) void mlp2_kernel(const int* __restrict__ sel2,
                                                      const u16* __restrict__ Thi,
                                                      const u16* __restrict__ Wt,
                                                      const float* __restrict__ b2,
                                                      float* __restrict__ out) {
    __shared__ u16 sA[2][128 * 32];   // 8 KiB each
    __shared__ u16 sB[2][256 * 32];   // 16 KiB each

    const int t = threadIdx.x;
    const int row0 = blockIdx.x * 128;
    const int col0 = blockIdx.y * 256;

    const int ar = t >> 2;            // 0..127
    const int ac8 = (t & 3) * 8;      // elem offset 0..24
    const int br = t >> 1;            // 0..255
    const int bc16 = (t & 1) * 16;    // elem offset 0/16

    const int trow = sel2[row0 + ar];
    const u16* Arow = &Thi[(size_t)trow * EXPR_D + ac8];
    const u16* Brow = &Wt[(size_t)(col0 + br) * EXPR_D + bc16];

    const int lane = t & 63;
    const int wid  = t >> 6;
    const int wr = wid >> 2, wc = wid & 3;
    const int lrow = lane & 15, lkg = lane >> 4;

    f32x4 acc[4][4];
    #pragma unroll
    for (int mi = 0; mi < 4; ++mi)
        #pragma unroll
        for (int ni = 0; ni < 4; ++ni)
            acc[mi][ni] = (f32x4){0.f, 0.f, 0.f, 0.f};

    u16x8 av;
    u16x8 bv[2];

    auto STAGE_ISSUE = [&](int kc) {
        const int kb = kc * 32;
        av = *(const u16x8*)&Arow[kb];
        bv[0] = *(const u16x8*)&Brow[kb];
        bv[1] = *(const u16x8*)&Brow[kb + 8];
    };

    auto WRITE = [&](int buf) {
        int aoff = ar * 64 + ((ac8 * 2) ^ ((ar & 3) << 4));
        *(u16x8*)((char*)sA[buf] + aoff) = av;
        #pragma unroll
        for (int j = 0; j < 2; ++j) {
            int boff = br * 64 + ((bc16 * 2 + j * 16) ^ ((br & 3) << 4));
            *(u16x8*)((char*)sB[buf] + boff) = bv[j];
        }
    };

    auto COMPUTE = [&](int buf) {
        s16x8 a[4], b[4];
        #pragma unroll
        for (int mi = 0; mi < 4; ++mi) {
            int row = wr * 64 + mi * 16 + lrow;
            int off = row * 64 + ((lkg * 16) ^ ((row & 3) << 4));
            a[mi] = *(const s16x8*)((const char*)sA[buf] + off);
        }
        #pragma unroll
        for (int ni = 0; ni < 4; ++ni) {
            int row = wc * 64 + ni * 16 + lrow;
            int off = row * 64 + ((lkg * 16) ^ ((row & 3) << 4));
            b[ni] = *(const s16x8*)((const char*)sB[buf] + off);
        }
        #pragma unroll
        for (int mi = 0; mi < 4; ++mi)
            #pragma unroll
            for (int ni = 0; ni < 4; ++ni)
                acc[mi][ni] = __builtin_amdgcn_mfma_f32_16x16x32_bf16(a[mi], b[ni], acc[mi][ni], 0, 0, 0);
    };

    STAGE_ISSUE(0);
    WRITE(0);
    __syncthreads();
    int cur = 0;
    #pragma unroll 1
    for (int kc = 0; kc < 16; ++kc) {
        if (kc < 15) STAGE_ISSUE(kc + 1);
        COMPUTE(cur);
        if (kc < 15) WRITE(cur ^ 1);
        __syncthreads();
        cur ^= 1;
    }

    #pragma unroll
    for (int ni = 0; ni < 4; ++ni) {
        int col = col0 + wc * 64 + ni * 16 + lrow;
        float bias = b2[col];
        #pragma unroll
        for (int mi = 0; mi < 4; ++mi) {
            int rbase = row0 + wr * 64 + mi * 16 + lkg * 4;
            #pragma unroll
            for (int j = 0; j < 4; ++j)
                out[(size_t)(rbase + j) * EXPR_D + col] = fmaxf(acc[mi][ni][j] + bias, 0.f);
        }
    }
}

extern "C" void kernel_launch(void* const* d_in, const int* in_sizes, int n_in,
                              void* d_out, int out_size, void* d_ws, size_t ws_size,
                              hipStream_t stream) {
    const int*   token_type = (const int*)d_in[0];
    const int*   kos_idx    = (const int*)d_in[1];
    const int*   id_idx     = (const int*)d_in[2];
    const float* enc_ids    = (const float*)d_in[3];
    const float* kind_emb   = (const float*)d_in[4];
    const float* kos_emb    = (const float*)d_in[5];
    const float* Wp         = (const float*)d_in[6];
    const float* bp         = (const float*)d_in[7];
    const float* W2         = (const float*)d_in[8];
    const float* b2         = (const float*)d_in[9];
    float* out = (float*)d_out;

    char* ws = (char*)d_ws;
    int*   sel2   = (int*)ws;                          // [0, 262144)
    float* kindc  = (float*)(ws + 262144);             // 16 KiB
    u16*   Thi    = (u16*)(ws + 278528);               // 9088*512*2 = 9306112
    u16*   Wt     = (u16*)(ws + 9584640);              // 512 KiB
    u16*   Wt1    = (u16*)(ws + 10108928);             // 256 KiB
    int2*  blkcnt = (int2*)(ws + 10371072);            // 2 KiB  (total ~10.4 MB)

    hipLaunchKernelGGL(prep_kernel, dim3(641), dim3(256), 0, stream,
                       W2, kind_emb, Wp, bp, token_type, Wt, Wt1, kindc, blkcnt);
    hipLaunchKernelGGL(scatter_kernel, dim3(256), dim3(256), 0, stream,
                       token_type, blkcnt, kos_idx, id_idx, sel2);
    hipLaunchKernelGGL(table_kernel, dim3(TROWS / 128, EXPR_D / 256), dim3(512), 0, stream,
                       enc_ids, kos_emb, Wt1, kindc, Thi);
    hipLaunchKernelGGL(mlp2_kernel, dim3(NPOS / 128, EXPR_D / 256), dim3(512), 0, stream,
                       sel2, Thi, Wt, b2, out);
}

// Round 6
// 75.849 us; speedup vs baseline: 7.7937x; 1.0858x over previous
//
#include <hip/hip_runtime.h>
#include <hip/hip_bf16.h>

#define BB 128
#define SS 512
#define NPOS (BB*SS)          // 65536
#define DD 256
#define KIND_D 8
#define EXPR_D 512
#define KOS_VOCAB 256
#define NUM_IDS 8192
#define IDENTIFIER_KIND 3
#define TROWS 9088            // padded table rows (8968 used) = 71*128

typedef unsigned short u16;
typedef __attribute__((ext_vector_type(8))) short s16x8;           // 8 bf16 (4 VGPRs)
typedef __attribute__((ext_vector_type(8))) unsigned short u16x8;  // 16B unit
typedef __attribute__((ext_vector_type(4))) float f32x4;

__device__ __forceinline__ u16 bf16bits(float v) {
    __hip_bfloat16 h = __float2bfloat16(v);
    return *(u16*)&h;
}
__device__ __forceinline__ float bf16tof(u16 b) {
    __hip_bfloat16 h = *(__hip_bfloat16*)&b;
    return __bfloat162float(h);
}

// ---------------- Kernel 1: prep ----------------
// blocks 0..255   : W2 [512k][512n] f32 -> Wt [n][k] bf16
// block  256      : kindc[kind][j] = kind_emb[kind] @ W_proj[0:8] + b_proj
// blocks 257..384 : W_proj[8:264] [256k][512n] f32 -> Wt1 [n][k] bf16
// blocks 385..640 : per-256-chunk {id,kos} counts of token_type -> blkcnt
__global__ __launch_bounds__(256) void prep_kernel(const float* __restrict__ W2,
                                                   const float* __restrict__ kind_emb,
                                                   const float* __restrict__ Wp,
                                                   const float* __restrict__ bp,
                                                   const int* __restrict__ token_type,
                                                   u16* __restrict__ Wt,
                                                   u16* __restrict__ Wt1,
                                                   float* __restrict__ kindc,
                                                   int2* __restrict__ blkcnt) {
    __shared__ float tile[32][33];
    __shared__ int swid[4], swkos[4];
    const int bi = blockIdx.x;
    const int t = threadIdx.x;

    if (bi < 256) {
        const int n0 = (bi & 15) * 32;
        const int k0 = (bi >> 4) * 32;
        const int lj = t & 31, li = t >> 5;
        #pragma unroll
        for (int p = 0; p < 4; ++p) {
            int i = li + p * 8;
            tile[i][lj] = W2[(size_t)(k0 + i) * EXPR_D + n0 + lj];
        }
        __syncthreads();
        #pragma unroll
        for (int p = 0; p < 4; ++p) {
            int j = li + p * 8;
            Wt[(size_t)(n0 + j) * EXPR_D + k0 + lj] = bf16bits(tile[lj][j]);
        }
    } else if (bi == 256) {
        #pragma unroll
        for (int rep = 0; rep < 2; ++rep) {
            int j = t + rep * 256;
            float bias = bp[j];
            for (int kind = 0; kind < 8; ++kind) {
                float a = bias;
                #pragma unroll
                for (int d = 0; d < KIND_D; ++d)
                    a = fmaf(kind_emb[kind * KIND_D + d], Wp[d * EXPR_D + j], a);
                kindc[kind * EXPR_D + j] = a;
            }
        }
    } else if (bi < 385) {
        const int idx = bi - 257;
        const int n0 = (idx & 15) * 32;
        const int k0 = (idx >> 4) * 32;
        const float* W1p = Wp + (size_t)KIND_D * EXPR_D;
        const int lj = t & 31, li = t >> 5;
        #pragma unroll
        for (int p = 0; p < 4; ++p) {
            int i = li + p * 8;
            tile[i][lj] = W1p[(size_t)(k0 + i) * EXPR_D + n0 + lj];
        }
        __syncthreads();
        #pragma unroll
        for (int p = 0; p < 4; ++p) {
            int j = li + p * 8;
            Wt1[(size_t)(n0 + j) * DD + k0 + lj] = bf16bits(tile[lj][j]);
        }
    } else {
        const int blk = bi - 385;
        const int lane = t & 63, wave = t >> 6;
        int k = token_type[blk * 256 + t];
        unsigned long long mid  = __ballot(k == IDENTIFIER_KIND);
        unsigned long long mkos = __ballot(k >= 4 && k <= 6);
        if (lane == 0) { swid[wave] = __popcll(mid); swkos[wave] = __popcll(mkos); }
        __syncthreads();
        if (t == 0) {
            int a = 0, c = 0;
            #pragma unroll
            for (int w = 0; w < 4; ++w) { a += swid[w]; c += swkos[w]; }
            blkcnt[blk] = make_int2(a, c);
        }
    }
}

// ---------------- Kernel 2: scatter -> sel2[] (direct table-row index) ----------------
// id rows: 0..8191 ; kos rows: 8192 + (kind-4)*256 + kos_idx ; none: 8960 + kind
__global__ __launch_bounds__(256) void scatter_kernel(const int* __restrict__ token_type,
                                                      const int2* __restrict__ blkcnt,
                                                      const int* __restrict__ kos_idx,
                                                      const int* __restrict__ id_idx,
                                                      int* __restrict__ sel2) {
    __shared__ int2 sbase;
    __shared__ int swid[4], swkos[4];
    const int b = blockIdx.x, t = threadIdx.x;
    const int lane = t & 63, wave = t >> 6;
    if (t < 64) {
        int a = 0, c = 0;
        for (int i = t; i < b; i += 64) { int2 v = blkcnt[i]; a += v.x; c += v.y; }
        #pragma unroll
        for (int off = 32; off; off >>= 1) { a += __shfl_down(a, off); c += __shfl_down(c, off); }
        if (t == 0) sbase = make_int2(a, c);
    }
    const int idx = b * 256 + t;
    const int k = token_type[idx];
    const bool fid  = (k == IDENTIFIER_KIND);
    const bool fkos = (k >= 4 && k <= 6);
    unsigned long long mid  = __ballot(fid);
    unsigned long long mkos = __ballot(fkos);
    if (lane == 0) { swid[wave] = __popcll(mid); swkos[wave] = __popcll(mkos); }
    __syncthreads();
    int bid = 0, bkos = 0;
    for (int w = 0; w < wave; ++w) { bid += swid[w]; bkos += swkos[w]; }
    unsigned long long below = (1ull << lane) - 1ull;
    int s;
    if (fid)       s = id_idx[sbase.x + bid + __popcll(mid & below)];
    else if (fkos) s = 8192 + (k - 4) * 256 + kos_idx[sbase.y + bkos + __popcll(mkos & below)];
    else           s = 8960 + k;
    sel2[idx] = s;
}

// ---------------- Kernel 3: build Thi = bf16(relu(kindc[kind] + x @ W1)) ----------------
// rows: 0..8191 = enc_ids (kind 3); 8192..8959 = kos (kind 4+q>>8); 8960..8967 = zero src.
__global__ __launch_bounds__(512, 2) void table_kernel(const float* __restrict__ enc_ids,
                                                       const float* __restrict__ kos_emb,
                                                       const u16* __restrict__ Wt1,
                                                       const float* __restrict__ kindc,
                                                       u16* __restrict__ Thi) {
    __shared__ u16 sAhi[2][128 * 64];
    __shared__ u16 sAlo[2][128 * 64];
    __shared__ u16 sB[2][256 * 64];

    const int t = threadIdx.x;
    const int row0 = blockIdx.x * 128;
    const int col0 = blockIdx.y * 256;

    const int ar = t >> 2;
    const int ac = (t & 3) * 16;
    const int br = t >> 1;
    const int bc = (t & 1) * 32;

    const int arow = row0 + ar;
    const float* Arow;
    bool hasrc = true;
    if (arow < NUM_IDS)        Arow = &enc_ids[(size_t)arow * DD];
    else if (arow < 8960)      Arow = &kos_emb[(size_t)((arow - NUM_IDS) & 255) * DD];
    else { Arow = enc_ids; hasrc = false; }
    const u16* Brow = &Wt1[(size_t)(col0 + br) * DD];

    const int lane = t & 63;
    const int wid  = t >> 6;
    const int wr = wid >> 2, wc = wid & 3;
    const int lrow = lane & 15, lkg = lane >> 4;

    f32x4 acc[4][4];
    #pragma unroll
    for (int mi = 0; mi < 4; ++mi)
        #pragma unroll
        for (int ni = 0; ni < 4; ++ni)
            acc[mi][ni] = (f32x4){0.f, 0.f, 0.f, 0.f};

    f32x4 av[4];
    u16x8 bv[4];

    auto STAGE_ISSUE = [&](int kc) {
        const int kb = kc * 64;
        #pragma unroll
        for (int j = 0; j < 4; ++j)
            av[j] = hasrc ? *(const f32x4*)&Arow[kb + ac + j * 4] : (f32x4){0.f,0.f,0.f,0.f};
        #pragma unroll
        for (int j = 0; j < 4; ++j) bv[j] = *(const u16x8*)&Brow[kb + bc + j * 8];
    };

    auto WRITE = [&](int buf) {
        u16 hi[16], lo[16];
        #pragma unroll
        for (int j = 0; j < 4; ++j)
            #pragma unroll
            for (int e = 0; e < 4; ++e) {
                float r = av[j][e];
                u16 h = bf16bits(r);
                hi[j * 4 + e] = h;
                lo[j * 4 + e] = bf16bits(r - bf16tof(h));
            }
        const int abase = ar * 128;
        const int o0 = abase + ((ac * 2) ^ ((ar & 7) << 4));
        const int o1 = abase + ((ac * 2 + 16) ^ ((ar & 7) << 4));
        *(u16x8*)((char*)sAhi[buf] + o0) = *(const u16x8*)&hi[0];
        *(u16x8*)((char*)sAhi[buf] + o1) = *(const u16x8*)&hi[8];
        *(u16x8*)((char*)sAlo[buf] + o0) = *(const u16x8*)&lo[0];
        *(u16x8*)((char*)sAlo[buf] + o1) = *(const u16x8*)&lo[8];
        const int bbase = br * 128;
        #pragma unroll
        for (int j = 0; j < 4; ++j) {
            int off = bbase + ((bc * 2 + j * 16) ^ ((br & 7) << 4));
            *(u16x8*)((char*)sB[buf] + off) = bv[j];
        }
    };

    auto COMPUTE = [&](int buf) {
        #pragma unroll
        for (int ks = 0; ks < 2; ++ks) {
            s16x8 ah[4], al[4], bbf[4];
            #pragma unroll
            for (int mi = 0; mi < 4; ++mi) {
                int row = wr * 64 + mi * 16 + lrow;
                int off = row * 128 + ((ks * 64 + lkg * 16) ^ ((row & 7) << 4));
                ah[mi] = *(const s16x8*)((const char*)sAhi[buf] + off);
                al[mi] = *(const s16x8*)((const char*)sAlo[buf] + off);
            }
            #pragma unroll
            for (int ni = 0; ni < 4; ++ni) {
                int row = wc * 64 + ni * 16 + lrow;
                int off = row * 128 + ((ks * 64 + lkg * 16) ^ ((row & 7) << 4));
                bbf[ni] = *(const s16x8*)((const char*)sB[buf] + off);
            }
            #pragma unroll
            for (int mi = 0; mi < 4; ++mi)
                #pragma unroll
                for (int ni = 0; ni < 4; ++ni) {
                    acc[mi][ni] = __builtin_amdgcn_mfma_f32_16x16x32_bf16(ah[mi], bbf[ni], acc[mi][ni], 0, 0, 0);
                    acc[mi][ni] = __builtin_amdgcn_mfma_f32_16x16x32_bf16(al[mi], bbf[ni], acc[mi][ni], 0, 0, 0);
                }
        }
    };

    STAGE_ISSUE(0);
    WRITE(0);
    __syncthreads();
    int cur = 0;
    #pragma unroll 1
    for (int kc = 0; kc < 4; ++kc) {
        if (kc < 3) STAGE_ISSUE(kc + 1);
        COMPUTE(cur);
        if (kc < 3) WRITE(cur ^ 1);
        __syncthreads();
        cur ^= 1;
    }

    // epilogue: add kindc[kind(row)], relu, bf16, store
    #pragma unroll
    for (int ni = 0; ni < 4; ++ni) {
        int col = col0 + wc * 64 + ni * 16 + lrow;
        #pragma unroll
        for (int mi = 0; mi < 4; ++mi) {
            int rbase = row0 + wr * 64 + mi * 16 + lkg * 4;
            #pragma unroll
            for (int j = 0; j < 4; ++j) {
                int rg = rbase + j;
                int kind = (rg < NUM_IDS) ? 3
                         : (rg < 8960) ? 4 + ((rg - NUM_IDS) >> 8)
                         : (rg < 8968) ? (rg - 8960) : 0;
                float v = acc[mi][ni][j] + kindc[kind * EXPR_D + col];
                Thi[(size_t)rg * EXPR_D + col] = bf16bits(fmaxf(v, 0.f));
            }
        }
    }
}

// ---------------- Kernel 4: O = relu(Thi @ Wt^T + b2)  (table-level layer 2) ----------
// BM=128, BN=256, BK=32 (16 chunks), 512 threads (2x4 waves), dbuf LDS = 48 KiB.
__global__ __launch_bounds__(512, 4) void table2_kernel(const u16* __restrict__ Thi,
                                                        const u16* __restrict__ Wt,
                                                        const float* __restrict__ b2,
                                                        float* __restrict__ O) {
    __shared__ u16 sA[2][128 * 32];
    __shared__ u16 sB[2][256 * 32];

    const int t = threadIdx.x;
    const int row0 = blockIdx.x * 128;
    const int col0 = blockIdx.y * 256;

    const int ar = t >> 2;
    const int ac8 = (t & 3) * 8;
    const int br = t >> 1;
    const int bc16 = (t & 1) * 16;

    const u16* Arow = &Thi[(size_t)(row0 + ar) * EXPR_D + ac8];
    const u16* Brow = &Wt[(size_t)(col0 + br) * EXPR_D + bc16];

    const int lane = t & 63;
    const int wid  = t >> 6;
    const int wr = wid >> 2, wc = wid & 3;
    const int lrow = lane & 15, lkg = lane >> 4;

    f32x4 acc[4][4];
    #pragma unroll
    for (int mi = 0; mi < 4; ++mi)
        #pragma unroll
        for (int ni = 0; ni < 4; ++ni)
            acc[mi][ni] = (f32x4){0.f, 0.f, 0.f, 0.f};

    u16x8 av;
    u16x8 bv[2];

    auto STAGE_ISSUE = [&](int kc) {
        const int kb = kc * 32;
        av = *(const u16x8*)&Arow[kb];
        bv[0] = *(const u16x8*)&Brow[kb];
        bv[1] = *(const u16x8*)&Brow[kb + 8];
    };

    auto WRITE = [&](int buf) {
        int aoff = ar * 64 + ((ac8 * 2) ^ ((ar & 3) << 4));
        *(u16x8*)((char*)sA[buf] + aoff) = av;
        #pragma unroll
        for (int j = 0; j < 2; ++j) {
            int boff = br * 64 + ((bc16 * 2 + j * 16) ^ ((br & 3) << 4));
            *(u16x8*)((char*)sB[buf] + boff) = bv[j];
        }
    };

    auto COMPUTE = [&](int buf) {
        s16x8 a[4], b[4];
        #pragma unroll
        for (int mi = 0; mi < 4; ++mi) {
            int row = wr * 64 + mi * 16 + lrow;
            int off = row * 64 + ((lkg * 16) ^ ((row & 3) << 4));
            a[mi] = *(const s16x8*)((const char*)sA[buf] + off);
        }
        #pragma unroll
        for (int ni = 0; ni < 4; ++ni) {
            int row = wc * 64 + ni * 16 + lrow;
            int off = row * 64 + ((lkg * 16) ^ ((row & 3) << 4));
            b[ni] = *(const s16x8*)((const char*)sB[buf] + off);
        }
        #pragma unroll
        for (int mi = 0; mi < 4; ++mi)
            #pragma unroll
            for (int ni = 0; ni < 4; ++ni)
                acc[mi][ni] = __builtin_amdgcn_mfma_f32_16x16x32_bf16(a[mi], b[ni], acc[mi][ni], 0, 0, 0);
    };

    STAGE_ISSUE(0);
    WRITE(0);
    __syncthreads();
    int cur = 0;
    #pragma unroll 1
    for (int kc = 0; kc < 16; ++kc) {
        if (kc < 15) STAGE_ISSUE(kc + 1);
        COMPUTE(cur);
        if (kc < 15) WRITE(cur ^ 1);
        __syncthreads();
        cur ^= 1;
    }

    #pragma unroll
    for (int ni = 0; ni < 4; ++ni) {
        int col = col0 + wc * 64 + ni * 16 + lrow;
        float bias = b2[col];
        #pragma unroll
        for (int mi = 0; mi < 4; ++mi) {
            int rbase = row0 + wr * 64 + mi * 16 + lkg * 4;
            #pragma unroll
            for (int j = 0; j < 4; ++j)
                O[(size_t)(rbase + j) * EXPR_D + col] = fmaxf(acc[mi][ni][j] + bias, 0.f);
        }
    }
}

// ---------------- Kernel 5: out[pos] = O[sel2[pos]]  (pure gather-copy) ----------
// 4 waves/block; each wave copies one 2KB row per iter via 2x float4/lane.
__global__ __launch_bounds__(256) void gather_kernel(const int* __restrict__ sel2,
                                                     const float* __restrict__ O,
                                                     float* __restrict__ out) {
    const int t = threadIdx.x;
    const int lane = t & 63, wave = t >> 6;
    const int base = blockIdx.x * 16;
    int rows[4];
    #pragma unroll
    for (int i = 0; i < 4; ++i) rows[i] = sel2[base + i * 4 + wave];
    #pragma unroll
    for (int i = 0; i < 4; ++i) {
        const int pos = base + i * 4 + wave;
        const f32x4* src = (const f32x4*)&O[(size_t)rows[i] * EXPR_D];
        f32x4* dst = (f32x4*)&out[(size_t)pos * EXPR_D];
        f32x4 v0 = src[lane];
        f32x4 v1 = src[lane + 64];
        __builtin_nontemporal_store(v0, &dst[lane]);
        __builtin_nontemporal_store(v1, &dst[lane + 64]);
    }
}

extern "C" void kernel_launch(void* const* d_in, const int* in_sizes, int n_in,
                              void* d_out, int out_size, void* d_ws, size_t ws_size,
                              hipStream_t stream) {
    const int*   token_type = (const int*)d_in[0];
    const int*   kos_idx    = (const int*)d_in[1];
    const int*   id_idx     = (const int*)d_in[2];
    const float* enc_ids    = (const float*)d_in[3];
    const float* kind_emb   = (const float*)d_in[4];
    const float* kos_emb    = (const float*)d_in[5];
    const float* Wp         = (const float*)d_in[6];
    const float* bp         = (const float*)d_in[7];
    const float* W2         = (const float*)d_in[8];
    const float* b2         = (const float*)d_in[9];
    float* out = (float*)d_out;

    char* ws = (char*)d_ws;
    int*   sel2   = (int*)ws;                          // 256 KiB
    float* kindc  = (float*)(ws + 262144);             // 16 KiB
    int2*  blkcnt = (int2*)(ws + 278528);              // 4 KiB
    u16*   Wt     = (u16*)(ws + 282624);               // 512 KiB
    u16*   Wt1    = (u16*)(ws + 806912);               // 256 KiB
    u16*   Thi    = (u16*)(ws + 1069056);              // TROWS*512*2 = 9306112
    float* O      = (float*)(ws + 10375168);           // TROWS*512*4 = 18612224 (~29 MB total)

    hipLaunchKernelGGL(prep_kernel, dim3(641), dim3(256), 0, stream,
                       W2, kind_emb, Wp, bp, token_type, Wt, Wt1, kindc, blkcnt);
    hipLaunchKernelGGL(scatter_kernel, dim3(256), dim3(256), 0, stream,
                       token_type, blkcnt, kos_idx, id_idx, sel2);
    hipLaunchKernelGGL(table_kernel, dim3(TROWS / 128, EXPR_D / 256), dim3(512), 0, stream,
                       enc_ids, kos_emb, Wt1, kindc, Thi);
    hipLaunchKernelGGL(table2_kernel, dim3(TROWS / 128, EXPR_D / 256), dim3(512), 0, stream,
                       Thi, Wt, b2, O);
    hipLaunchKernelGGL(gather_kernel, dim3(NPOS / 16), dim3(256), 0, stream,
                       sel2, O, out);
}